// Round 20
// baseline (634.592 us; speedup 1.0000x reference)
//
#include <hip/hip_runtime.h>

typedef _Float16 f16;
typedef _Float16 f16x4 __attribute__((ext_vector_type(4)));
typedef _Float16 f16x8 __attribute__((ext_vector_type(8)));
typedef float    f32x16 __attribute__((ext_vector_type(16)));
typedef int      i32x4 __attribute__((ext_vector_type(4)));

#define B_ 4
#define H_ 16
#define S_ 2048
#define D_ 128
#define KVB 32
#define KSTR 136      // 272B = 17x16B slots, odd -> min-aliasing b128
#define VTSTR 40      // 80B  =  5x16B slots, odd -> min-aliasing b128

union U4 { i32x4 i; f16x8 h; };

__device__ __forceinline__ unsigned pk2(float a, float b) {
    auto v = __builtin_amdgcn_cvt_pkrtz(a, b);
    return __builtin_bit_cast(unsigned, v);
}

__device__ __forceinline__ f16x8 cvt8(const float4 a, const float4 b) {
    f16x8 h;
    h[0] = (f16)a.x; h[1] = (f16)a.y; h[2] = (f16)a.z; h[3] = (f16)a.w;
    h[4] = (f16)b.x; h[5] = (f16)b.y; h[6] = (f16)b.z; h[7] = (f16)b.w;
    return h;
}

// ---- pre-pass: K -> f16 row-major PRE-SCALED by 1/sqrt(128)*log2e; V -> f16 pi-permuted ----
// Vtt: [bh][t32=k/32][d][pos0..31]; per 16-pos chunk: pos0-3<-k0-3, pos4-7<-k8-11,
// pos8-11<-k4-7, pos12-15<-k12-15 (matches un-exchanged P A-frag, pi(h,j)=4h+(j&3)+8(j>>2))
__global__ __launch_bounds__(256)
void prep(const float* __restrict__ K, const float* __restrict__ V,
          f16* __restrict__ Kh, f16* __restrict__ Vtt)
{
    const int bid = blockIdx.x;
    const int bh  = bid >> 5;
    const int kb  = bid & 31;
    const int k0  = kb * 64;
    const int tid = threadIdx.x;
    const float qmul = 0.08838834764831845f * 1.4426950408889634f;

    const float* Kb = K + ((size_t)bh * S_ + k0) * D_;
    const float* Vb = V + ((size_t)bh * S_ + k0) * D_;
    f16* Khb = Kh + ((size_t)bh * S_ + k0) * D_;
    f16* Vtb = Vtt + (size_t)bh * S_ * D_ + (size_t)kb * 2 * (D_ * 32);

    #pragma unroll
    for (int it = 0; it < 4; ++it) {
        const int idx = tid + it * 256;
        const int row = idx >> 4, c8 = idx & 15;
        float4 a = *(const float4*)(Kb + row * D_ + c8 * 8);
        float4 b = *(const float4*)(Kb + row * D_ + c8 * 8 + 4);
        a.x *= qmul; a.y *= qmul; a.z *= qmul; a.w *= qmul;
        b.x *= qmul; b.y *= qmul; b.z *= qmul; b.w *= qmul;
        *(f16x8*)(Khb + row * D_ + c8 * 8) = cvt8(a, b);
    }
    #pragma unroll
    for (int it = 0; it < 4; ++it) {
        const int idx = tid + it * 256;
        const int d  = idx & 127;
        const int k8 = idx >> 7;
        const int t  = k8 >> 2;
        const int o  = k8 & 3;
        const int c  = o >> 1, odd = o & 1;
        const int kbase = t * 32 + c * 16 + odd * 4;
        const float* vp0 = Vb + (size_t)kbase * D_ + d;
        const float* vp1 = vp0 + (size_t)8 * D_;
        f16x8 vh;
        #pragma unroll
        for (int e = 0; e < 4; ++e) vh[e] = (f16)vp0[(size_t)e * D_];
        #pragma unroll
        for (int e = 0; e < 4; ++e) vh[4 + e] = (f16)vp1[(size_t)e * D_];
        *(f16x8*)(Vtb + (size_t)t * (D_ * 32) + d * 32 + o * 8) = vh;
    }
}

// ---- main: split-KV (2048 blocks, 3 blocks/CU) with FUSED finisher merge ----
__global__ __launch_bounds__(256, 3)
void fattn19(const float* __restrict__ Qg, const f16* __restrict__ Khg,
             const f16* __restrict__ Vttg, float* __restrict__ Og,
             f16* __restrict__ Pg, float2* __restrict__ mlg, int* __restrict__ flags)
{
    __shared__ __align__(16) f16 Klds[2][KVB * KSTR];   // 17408 B
    __shared__ __align__(16) f16 Vl[2][128 * VTSTR];    // 20480 B  (37888 total)
    __shared__ int oldv;

    // 2048 blocks: xcd-clustered per bh, qt descending (LPT), s = KV half
    const int id  = blockIdx.x;
    const int xcd = id & 7;
    const int r   = id >> 3;             // 0..255
    const int bh  = xcd + 8 * (r & 7);
    const int rr  = r >> 3;              // 0..31
    const int s   = rr & 1;
    const int qt  = 15 - (rr >> 1);

    const int tid  = threadIdx.x;
    const int lane = tid & 63;
    const int l31  = lane & 31;
    const int h    = lane >> 5;
    const int wv   = tid >> 6;

    const int qw0 = qt * 128 + wv * 32;
    const int qg  = qw0 + l31;

    const float* Qb  = Qg  + (size_t)bh * S_ * D_;
    const f16*   Khb = Khg + (size_t)bh * S_ * D_;
    const f16*   Vtb = Vttg + (size_t)bh * S_ * D_;

    const int nkt  = 4 * qt + 4;
    const int half = 2 * qt + 2;
    const int lo   = s ? half : 0;
    const int hi   = s ? nkt : half;
    int lastt = 4 * qt + wv;             // wave-uniform causal bound
    if (lastt > hi - 1) lastt = hi - 1;

    // hoisted staging addresses
    const f16* kS = Khb + (tid >> 4) * D_ + (tid & 15) * 8;
    const f16* vS = Vtb + (size_t)tid * 8;
    const int  kDo = (tid >> 4) * KSTR + (tid & 15) * 8;
    const int  vDo = (tid >> 2) * VTSTR + (tid & 3) * 8;

    i32x4 kr[2], vr[2];
    auto issue = [&](int kt) {
        const f16* kp = kS + ((size_t)kt << 12);
        const f16* vp = vS + ((size_t)kt << 12);
        kr[0] = *(const i32x4*)kp;
        kr[1] = *(const i32x4*)(kp + 2048);
        vr[0] = *(const i32x4*)vp;
        vr[1] = *(const i32x4*)(vp + 2048);
    };
    auto writeLds = [&](int buf) {
        f16* kb = &Klds[buf][0];
        f16* vb = &Vl[buf][0];
        *(i32x4*)(kb + kDo)              = kr[0];
        *(i32x4*)(kb + kDo + 16 * KSTR)  = kr[1];
        *(i32x4*)(vb + vDo)              = vr[0];
        *(i32x4*)(vb + vDo + 64 * VTSTR) = vr[1];
    };

    // Q fragments: fp32 load + cvt (scale folded into K at prep)
    f16x8 qf[8];
    {
        const float* Qrow = Qb + (size_t)(qw0 + l31) * D_;
        #pragma unroll
        for (int dc = 0; dc < 8; ++dc) {
            const float4 a = *(const float4*)(Qrow + dc * 16 + h * 8);
            const float4 b = *(const float4*)(Qrow + dc * 16 + h * 8 + 4);
            qf[dc] = cvt8(a, b);
        }
    }

    f32x16 acc[4];
    #pragma unroll
    for (int dt = 0; dt < 4; ++dt)
        #pragma unroll
        for (int q = 0; q < 16; ++q) acc[dt][q] = 0.f;
    float m_i = -1e30f, l_i = 0.f;

    issue(lo);
    writeLds(0);
    if (lo + 1 < hi) issue(lo + 1);
    __syncthreads();

    for (int kt = lo; kt < hi; ++kt) {
        const int cur = (kt - lo) & 1;

        if (kt <= lastt) {
            const int k0 = kt * KVB;
            f32x16 sv;
            #pragma unroll
            for (int q = 0; q < 16; ++q) sv[q] = 0.f;
            __builtin_amdgcn_s_setprio(1);
            #pragma unroll
            for (int dc = 0; dc < 8; ++dc) {
                const f16x8 kf = *(const f16x8*)&Klds[cur][l31 * KSTR + dc * 16 + h * 8];
                sv = __builtin_amdgcn_mfma_f32_32x32x16_f16(kf, qf[dc], sv, 0, 0, 0);
            }
            __builtin_amdgcn_s_setprio(0);
            if (k0 + 31 > qw0) {
                #pragma unroll
                for (int q = 0; q < 16; ++q) {
                    const int kg = k0 + (q & 3) + 8 * (q >> 2) + 4 * h;
                    if (kg > qg) sv[q] = -1e30f;
                }
            }
            // row max (tree) + cross-half
            const float a1 = fmaxf(fmaxf(sv[0], sv[1]), sv[2]);
            const float a2 = fmaxf(fmaxf(sv[3], sv[4]), sv[5]);
            const float a3 = fmaxf(fmaxf(sv[6], sv[7]), sv[8]);
            const float a4 = fmaxf(fmaxf(sv[9], sv[10]), sv[11]);
            const float a5 = fmaxf(fmaxf(sv[12], sv[13]), sv[14]);
            float mx = fmaxf(fmaxf(a1, a2), a3);
            mx = fmaxf(fmaxf(mx, a4), a5);
            mx = fmaxf(mx, sv[15]);
            mx = fmaxf(mx, __shfl_xor(mx, 32));
            if (!__all(mx - m_i <= 8.0f)) {       // defer-max (T13)
                const float mn = fmaxf(m_i, mx);
                const float al = exp2f(m_i - mn);
                m_i = mn;
                l_i *= al;
                float arow[16];
                #pragma unroll
                for (int q = 0; q < 16; ++q)
                    arow[q] = __shfl(al, (q & 3) + 8 * (q >> 2) + 4 * h);
                #pragma unroll
                for (int dt = 0; dt < 4; ++dt)
                    #pragma unroll
                    for (int q = 0; q < 16; ++q) acc[dt][q] *= arow[q];
            }
            #pragma unroll
            for (int q = 0; q < 16; ++q) sv[q] = exp2f(sv[q] - m_i);
            float s8[8];
            #pragma unroll
            for (int q = 0; q < 8; ++q) s8[q] = sv[2 * q] + sv[2 * q + 1];
            #pragma unroll
            for (int q = 0; q < 4; ++q) s8[q] += s8[q + 4];
            s8[0] += s8[2]; s8[1] += s8[3];
            float rsum = s8[0] + s8[1];
            rsum += __shfl_xor(rsum, 32);
            l_i += rsum;
            // zero-shuffle pack (pi-permuted V matches)
            U4 pa0, pa1;
            #pragma unroll
            for (int m = 0; m < 4; ++m) {
                pa0.i[m] = (int)pk2(sv[2 * m],     sv[2 * m + 1]);
                pa1.i[m] = (int)pk2(sv[8 + 2 * m], sv[9 + 2 * m]);
            }
            // PV
            __builtin_amdgcn_s_setprio(1);
            #pragma unroll
            for (int dt = 0; dt < 4; ++dt) {
                const f16* vrow = &Vl[cur][(dt * 32 + l31) * VTSTR + h * 8];
                const f16x8 b0 = *(const f16x8*)(vrow + 0);
                const f16x8 b1 = *(const f16x8*)(vrow + 16);
                acc[dt] = __builtin_amdgcn_mfma_f32_32x32x16_f16(pa0.h, b0, acc[dt], 0, 0, 0);
                acc[dt] = __builtin_amdgcn_mfma_f32_32x32x16_f16(pa1.h, b1, acc[dt], 0, 0, 0);
            }
            __builtin_amdgcn_s_setprio(0);
        }

        if (kt + 1 < hi) {
            writeLds(cur ^ 1);
            if (kt + 2 < hi) issue(kt + 2);
            __syncthreads();
        }
    }

    // ---- publish normalized f16 partial + (m,l)
    float li[16];
    #pragma unroll
    for (int q = 0; q < 16; ++q) {
        const float lv = __shfl(l_i, (q & 3) + 8 * (q >> 2) + 4 * h);
        li[q] = (lv > 0.f) ? 1.0f / lv : 0.f;
    }
    f16* Pb = Pg + ((size_t)s * (B_ * H_) + bh) * (S_ * D_);
    #pragma unroll
    for (int dt = 0; dt < 4; ++dt)
        #pragma unroll
        for (int q = 0; q < 16; ++q) {
            const int row = qw0 + (q & 3) + 8 * (q >> 2) + 4 * h;
            Pb[(size_t)row * D_ + dt * 32 + l31] = (f16)(acc[dt][q] * li[q]);
        }
    if (h == 0)
        mlg[((size_t)s * (B_ * H_) + bh) * S_ + qw0 + l31] = make_float2(m_i, l_i);

    // ---- finisher-block fused merge (device-scope ticket)
    __threadfence();                 // release: all this block's P/ml stores
    __syncthreads();
    if (tid == 0) oldv = atomicAdd(&flags[bh * 16 + qt], 1);
    __syncthreads();
    if (oldv == 1) {
        __threadfence();             // acquire: other split's P/ml visible
        const f16* P0 = Pg + (size_t)bh * (S_ * D_);
        const f16* P1 = Pg + ((size_t)(B_ * H_) + bh) * (S_ * D_);
        const float2* ml0 = mlg + (size_t)bh * S_;
        const float2* ml1 = mlg + ((size_t)(B_ * H_) + bh) * S_;
        float* Ob = Og + (size_t)bh * S_ * D_;
        #pragma unroll
        for (int it = 0; it < 16; ++it) {
            const int i   = tid + it * 256;        // 0..4095 float4 chunks
            const int row = qt * 128 + (i >> 5);
            const int c4  = i & 31;
            const float2 a = ml0[row];
            const float2 b = ml1[row];
            const float ms = fmaxf(a.x, b.x);
            float w0 = exp2f(a.x - ms) * a.y;
            float w1 = exp2f(b.x - ms) * b.y;
            const float inv = 1.0f / (w0 + w1);
            w0 *= inv; w1 *= inv;
            const f16x4 p0 = *(const f16x4*)(P0 + (size_t)row * D_ + c4 * 4);
            const f16x4 p1 = *(const f16x4*)(P1 + (size_t)row * D_ + c4 * 4);
            float4 o;
            o.x = w0 * (float)p0[0] + w1 * (float)p1[0];
            o.y = w0 * (float)p0[1] + w1 * (float)p1[1];
            o.z = w0 * (float)p0[2] + w1 * (float)p1[2];
            o.w = w0 * (float)p0[3] + w1 * (float)p1[3];
            *(float4*)(Ob + (size_t)row * D_ + c4 * 4) = o;
        }
    }
}

// ---- fallback (tiny ws): f32 in-loop staging, single pass ----
__global__ __launch_bounds__(256, 3)
void fattn5(const float* __restrict__ Qg, const float* __restrict__ Kg,
            const float* __restrict__ Vg, float* __restrict__ Og)
{
    __shared__ __align__(16) f16 Klds[2][KVB * KSTR];
    __shared__ __align__(16) f16 Vt[2][128 * VTSTR];
    const int id  = blockIdx.x;
    const int xcd = id & 7;
    const int w   = id >> 3;
    const int qt  = 15 - (w & 15);
    const int bh  = xcd + 8 * (w >> 4);
    const int tid  = threadIdx.x;
    const int lane = tid & 63;
    const int wv   = tid >> 6;
    const int l31  = lane & 31;
    const int h    = lane >> 5;
    const int qw0 = qt * 128 + wv * 32;
    const int qg  = qw0 + l31;
    const size_t base = (size_t)bh * S_ * D_;
    const float* Qb = Qg + base;
    const float* Kb = Kg + base;
    const float* Vb = Vg + base;
    float*       Ob = Og + base;
    const int nkt = 4 * qt + 4;
    float4 kr[4];
    float  vr[16];
    auto issue = [&](int kt) {
        const int k0n = kt * KVB;
        #pragma unroll
        for (int it = 0; it < 2; ++it) {
            const int idx  = tid + it * 256;
            const int krow = idx >> 4;
            const int c8   = idx & 15;
            const float* kp = Kb + (size_t)(k0n + krow) * D_ + c8 * 8;
            kr[it * 2]     = *(const float4*)kp;
            kr[it * 2 + 1] = *(const float4*)(kp + 4);
            const int d  = idx & 127;
            const int k8 = idx >> 7;
            const float* vp = Vb + (size_t)(k0n + k8 * 8) * D_ + d;
            #pragma unroll
            for (int e = 0; e < 8; ++e) vr[it * 8 + e] = vp[(size_t)e * D_];
        }
    };
    auto writeLds = [&](int buf) {
        #pragma unroll
        for (int it = 0; it < 2; ++it) {
            const int idx  = tid + it * 256;
            const int krow = idx >> 4;
            const int c8   = idx & 15;
            *(f16x8*)&Klds[buf][krow * KSTR + c8 * 8] = cvt8(kr[it * 2], kr[it * 2 + 1]);
            const int d  = idx & 127;
            const int k8 = idx >> 7;
            f16x8 vh;
            #pragma unroll
            for (int e = 0; e < 8; ++e) vh[e] = (f16)vr[it * 8 + e];
            *(f16x8*)&Vt[buf][d * VTSTR + k8 * 8] = vh;
        }
    };
    const float qmul = 0.08838834764831845f * 1.4426950408889634f;
    f16x8 qf[8];
    {
        const float* Qrow = Qb + (size_t)(qw0 + l31) * D_;
        #pragma unroll
        for (int dc = 0; dc < 8; ++dc) {
            const float4 a = *(const float4*)(Qrow + dc * 16 + h * 8);
            const float4 b = *(const float4*)(Qrow + dc * 16 + h * 8 + 4);
            f16x8 q;
            q[0] = (f16)(a.x * qmul); q[1] = (f16)(a.y * qmul);
            q[2] = (f16)(a.z * qmul); q[3] = (f16)(a.w * qmul);
            q[4] = (f16)(b.x * qmul); q[5] = (f16)(b.y * qmul);
            q[6] = (f16)(b.z * qmul); q[7] = (f16)(b.w * qmul);
            qf[dc] = q;
        }
    }
    f32x16 acc[4];
    #pragma unroll
    for (int dt = 0; dt < 4; ++dt)
        #pragma unroll
        for (int q = 0; q < 16; ++q) acc[dt][q] = 0.f;
    float m_i = -1e30f, l_i = 0.f;
    issue(0);
    writeLds(0);
    if (nkt > 1) issue(1);
    __syncthreads();
    for (int kt = 0; kt < nkt; ++kt) {
        const int k0  = kt * KVB;
        const int cur = kt & 1;
        if (k0 <= qw0 + 31) {
            f32x16 sv;
            #pragma unroll
            for (int q = 0; q < 16; ++q) sv[q] = 0.f;
            #pragma unroll
            for (int dc = 0; dc < 8; ++dc) {
                const f16x8 kf = *(const f16x8*)&Klds[cur][l31 * KSTR + dc * 16 + h * 8];
                sv = __builtin_amdgcn_mfma_f32_32x32x16_f16(kf, qf[dc], sv, 0, 0, 0);
            }
            if (k0 + 31 > qw0) {
                #pragma unroll
                for (int q = 0; q < 16; ++q) {
                    const int kg = k0 + (q & 3) + 8 * (q >> 2) + 4 * h;
                    if (kg > qg) sv[q] = -1e30f;
                }
            }
            float mx = sv[0];
            #pragma unroll
            for (int q = 1; q < 16; ++q) mx = fmaxf(mx, sv[q]);
            mx = fmaxf(mx, __shfl_xor(mx, 32));
            if (!__all(mx - m_i <= 8.0f)) {
                const float mn = fmaxf(m_i, mx);
                const float al = exp2f(m_i - mn);
                m_i = mn;
                l_i *= al;
                float arow[16];
                #pragma unroll
                for (int q = 0; q < 16; ++q)
                    arow[q] = __shfl(al, (q & 3) + 8 * (q >> 2) + 4 * h);
                #pragma unroll
                for (int dt = 0; dt < 4; ++dt)
                    #pragma unroll
                    for (int q = 0; q < 16; ++q) acc[dt][q] *= arow[q];
            }
            float rsum = 0.f;
            #pragma unroll
            for (int q = 0; q < 16; ++q) {
                sv[q] = exp2f(sv[q] - m_i);
                rsum += sv[q];
            }
            rsum += __shfl_xor(rsum, 32);
            l_i += rsum;
            U4 pa[2];
            {
                unsigned dwp[8];
                #pragma unroll
                for (int m = 0; m < 8; ++m) dwp[m] = pk2(sv[2 * m], sv[2 * m + 1]);
                #pragma unroll
                for (int hf = 0; hf < 2; ++hf) {
                    const unsigned a0 = dwp[hf * 4 + 0], a1 = dwp[hf * 4 + 1];
                    const unsigned b0 = dwp[hf * 4 + 2], b1 = dwp[hf * 4 + 3];
                    const unsigned sa0 = (unsigned)__shfl_xor((int)a0, 32);
                    const unsigned sa1 = (unsigned)__shfl_xor((int)a1, 32);
                    const unsigned sb0 = (unsigned)__shfl_xor((int)b0, 32);
                    const unsigned sb1 = (unsigned)__shfl_xor((int)b1, 32);
                    i32x4 d;
                    d[0] = h ? (int)sb0 : (int)a0;
                    d[1] = h ? (int)sb1 : (int)a1;
                    d[2] = h ? (int)b0  : (int)sa0;
                    d[3] = h ? (int)b1  : (int)sa1;
                    pa[hf].i = d;
                }
            }
            #pragma unroll
            for (int dt = 0; dt < 4; ++dt) {
                const f16* vrow = &Vt[cur][(dt * 32 + l31) * VTSTR + h * 8];
                const f16x8 vb0 = *(const f16x8*)(vrow + 0);
                const f16x8 vb1 = *(const f16x8*)(vrow + 16);
                acc[dt] = __builtin_amdgcn_mfma_f32_32x32x16_f16(pa[0].h, vb0, acc[dt], 0, 0, 0);
                acc[dt] = __builtin_amdgcn_mfma_f32_32x32x16_f16(pa[1].h, vb1, acc[dt], 0, 0, 0);
            }
        }
        if (kt + 1 < nkt) {
            writeLds(cur ^ 1);
            if (kt + 2 < nkt) issue(kt + 2);
            __syncthreads();
        }
    }
    float li[16];
    #pragma unroll
    for (int q = 0; q < 16; ++q) {
        const float lv = __shfl(l_i, (q & 3) + 8 * (q >> 2) + 4 * h);
        li[q] = 1.0f / lv;
    }
    #pragma unroll
    for (int dt = 0; dt < 4; ++dt)
        #pragma unroll
        for (int q = 0; q < 16; ++q) {
            const int row = qw0 + (q & 3) + 8 * (q >> 2) + 4 * h;
            Ob[(size_t)row * D_ + dt * 32 + l31] = acc[dt][q] * li[q];
        }
}

extern "C" void kernel_launch(void* const* d_in, const int* in_sizes, int n_in,
                              void* d_out, int out_size, void* d_ws, size_t ws_size,
                              hipStream_t stream) {
    (void)in_sizes; (void)n_in; (void)out_size;
    const float* Q = (const float*)d_in[0];
    const float* K = (const float*)d_in[1];
    const float* V = (const float*)d_in[2];
    float* O = (float*)d_out;
    const size_t elems = (size_t)B_ * H_ * S_ * D_;
    const size_t nrow  = (size_t)B_ * H_ * S_;
    const size_t need  = elems * 2 * 4                  // Kh, Vtt, P[2]  (f16)
                       + nrow * 2 * sizeof(float2)      // ml[2]
                       + 1024 * sizeof(int);            // flags
    if (ws_size >= need) {
        f16* Kh  = (f16*)d_ws;
        f16* Vtt = Kh + elems;
        f16* P   = Vtt + elems;                 // [2][bh][row][d]
        float2* ml = (float2*)(P + 2 * elems);  // [2][bh*S]
        int* flags = (int*)(ml + 2 * nrow);     // [bh*16+qt]
        hipMemsetAsync(flags, 0, 1024 * sizeof(int), stream);
        prep<<<dim3(B_ * H_ * (S_ / 64)), dim3(256), 0, stream>>>(K, V, Kh, Vtt);
        fattn19<<<dim3(2048), dim3(256), 0, stream>>>(Q, Kh, Vtt, O, P, ml, flags);
    } else {
        fattn5<<<dim3((S_ / 128) * B_ * H_), dim3(256), 0, stream>>>(Q, K, V, O);
    }
}

// Round 21
// 154.479 us; speedup vs baseline: 4.1080x; 4.1080x over previous
//
#include <hip/hip_runtime.h>

typedef _Float16 f16;
typedef _Float16 f16x8 __attribute__((ext_vector_type(8)));
typedef float    f32x16 __attribute__((ext_vector_type(16)));
typedef int      i32x4 __attribute__((ext_vector_type(4)));

#define B_ 4
#define H_ 16
#define S_ 2048
#define D_ 128
#define KVB 32
#define KSTR 136      // 272B = 17x16B slots, odd -> min-aliasing b128
#define VTSTR 40      // 80B  =  5x16B slots, odd -> min-aliasing b128

union U4 { i32x4 i; f16x8 h; };

__device__ __forceinline__ unsigned pk2(float a, float b) {
    auto v = __builtin_amdgcn_cvt_pkrtz(a, b);
    return __builtin_bit_cast(unsigned, v);
}

__device__ __forceinline__ f16x8 cvt8(const float4 a, const float4 b) {
    f16x8 h;
    h[0] = (f16)a.x; h[1] = (f16)a.y; h[2] = (f16)a.z; h[3] = (f16)a.w;
    h[4] = (f16)b.x; h[5] = (f16)b.y; h[6] = (f16)b.z; h[7] = (f16)b.w;
    return h;
}

// ---- pre-pass: K -> f16 row-major PRE-SCALED by 1/sqrt(128)*log2e; V -> f16 pi-permuted ----
// Vtt: [bh][t=k/32][d][pos 0..31]; per 16-pos chunk: pos0-3<-k0-3, pos4-7<-k8-11,
// pos8-11<-k4-7, pos12-15<-k12-15  (matches un-exchanged P A-fragment, pi(h,j)=4h+(j&3)+8(j>>2))
__global__ __launch_bounds__(256)
void prep(const float* __restrict__ K, const float* __restrict__ V,
          f16* __restrict__ Kh, f16* __restrict__ Vtt)
{
    const int bid = blockIdx.x;
    const int bh  = bid >> 5;
    const int kb  = bid & 31;
    const int k0  = kb * 64;
    const int tid = threadIdx.x;
    const float qmul = 0.08838834764831845f * 1.4426950408889634f;

    const float* Kb = K + ((size_t)bh * S_ + k0) * D_;
    const float* Vb = V + ((size_t)bh * S_ + k0) * D_;
    f16* Khb = Kh + ((size_t)bh * S_ + k0) * D_;
    f16* Vtb = Vtt + (size_t)bh * S_ * D_ + (size_t)kb * 2 * (D_ * 32);

    #pragma unroll
    for (int it = 0; it < 4; ++it) {
        const int idx = tid + it * 256;
        const int row = idx >> 4, c8 = idx & 15;
        float4 a = *(const float4*)(Kb + row * D_ + c8 * 8);
        float4 b = *(const float4*)(Kb + row * D_ + c8 * 8 + 4);
        a.x *= qmul; a.y *= qmul; a.z *= qmul; a.w *= qmul;
        b.x *= qmul; b.y *= qmul; b.z *= qmul; b.w *= qmul;
        *(f16x8*)(Khb + row * D_ + c8 * 8) = cvt8(a, b);
    }
    #pragma unroll
    for (int it = 0; it < 4; ++it) {
        const int idx = tid + it * 256;
        const int d  = idx & 127;
        const int k8 = idx >> 7;              // octet index: t = k8>>2, o = k8&3
        const int t  = k8 >> 2;
        const int o  = k8 & 3;
        const int c  = o >> 1, odd = o & 1;
        const int kbase = t * 32 + c * 16 + odd * 4;
        const float* vp0 = Vb + (size_t)kbase * D_ + d;
        const float* vp1 = vp0 + (size_t)8 * D_;
        f16x8 vh;
        #pragma unroll
        for (int e = 0; e < 4; ++e) vh[e] = (f16)vp0[(size_t)e * D_];
        #pragma unroll
        for (int e = 0; e < 4; ++e) vh[4 + e] = (f16)vp1[(size_t)e * D_];
        *(f16x8*)(Vtb + (size_t)t * (D_ * 32) + d * 32 + o * 8) = vh;
    }
}

// ------- main: paired q-tiles, dual-stream, 3-buffer single-barrier, batched LDS reads -------
__global__ __launch_bounds__(256, 2)
void fattn20(const float* __restrict__ Qg, const f16* __restrict__ Khg,
             const f16* __restrict__ Vttg, float* __restrict__ Og)
{
    __shared__ __align__(16) f16 Klds[3][KVB * KSTR];   // 26112 B
    __shared__ __align__(16) f16 Vt[3][128 * VTSTR];    // 30720 B (total 56832)

    // 512 blocks: xcd = id&7, bh = xcd + 8*(r&7), pair p = r>>3
    const int id  = blockIdx.x;
    const int xcd = id & 7;
    const int r   = id >> 3;
    const int bh  = xcd + 8 * (r & 7);
    const int p   = r >> 3;              // 0..7

    const int tid  = threadIdx.x;
    const int lane = tid & 63;
    const int l31  = lane & 31;
    const int h    = lane >> 5;
    const int wv   = tid >> 6;

    const float* Qb  = Qg   + (size_t)bh * S_ * D_;
    const f16*   Khb = Khg  + (size_t)bh * S_ * D_;
    const f16*   Vtb = Vttg + (size_t)bh * S_ * D_;
    float*       Ob  = Og   + (size_t)bh * S_ * D_;

    // hoisted staging addresses
    const f16* kS = Khb + (tid >> 4) * D_ + (tid & 15) * 8;
    const f16* vS = Vtb + (size_t)tid * 8;
    const int  kDo = (tid >> 4) * KSTR + (tid & 15) * 8;
    const int  vDo = (tid >> 2) * VTSTR + (tid & 3) * 8;

    i32x4 kr[2], vr[2];
    auto issue = [&](int kt) {
        const f16* kp = kS + ((size_t)kt << 12);
        const f16* vp = vS + ((size_t)kt << 12);
        kr[0] = *(const i32x4*)kp;
        kr[1] = *(const i32x4*)(kp + 2048);
        vr[0] = *(const i32x4*)vp;
        vr[1] = *(const i32x4*)(vp + 2048);
    };
    auto writeLds = [&](int buf) {
        f16* kb = &Klds[buf][0];
        f16* vb = &Vt[buf][0];
        *(i32x4*)(kb + kDo)              = kr[0];
        *(i32x4*)(kb + kDo + 16 * KSTR)  = kr[1];
        *(i32x4*)(vb + vDo)              = vr[0];
        *(i32x4*)(vb + vDo + 64 * VTSTR) = vr[1];
    };
    f16x8 qf[8];
    auto qkt = [&](int buf) {
        const f16* base = &Klds[buf][l31 * KSTR + h * 8];
        f16x8 kf0 = *(const f16x8*)(base + 0 * 16);
        f16x8 kf1 = *(const f16x8*)(base + 1 * 16);
        f16x8 kf2 = *(const f16x8*)(base + 2 * 16);
        f16x8 kf3 = *(const f16x8*)(base + 3 * 16);
        f16x8 kf4 = *(const f16x8*)(base + 4 * 16);
        f16x8 kf5 = *(const f16x8*)(base + 5 * 16);
        f16x8 kf6 = *(const f16x8*)(base + 6 * 16);
        f16x8 kf7 = *(const f16x8*)(base + 7 * 16);
        f32x16 a;
        #pragma unroll
        for (int q = 0; q < 16; ++q) a[q] = 0.f;
        a = __builtin_amdgcn_mfma_f32_32x32x16_f16(kf0, qf[0], a, 0, 0, 0);
        a = __builtin_amdgcn_mfma_f32_32x32x16_f16(kf1, qf[1], a, 0, 0, 0);
        a = __builtin_amdgcn_mfma_f32_32x32x16_f16(kf2, qf[2], a, 0, 0, 0);
        a = __builtin_amdgcn_mfma_f32_32x32x16_f16(kf3, qf[3], a, 0, 0, 0);
        a = __builtin_amdgcn_mfma_f32_32x32x16_f16(kf4, qf[4], a, 0, 0, 0);
        a = __builtin_amdgcn_mfma_f32_32x32x16_f16(kf5, qf[5], a, 0, 0, 0);
        a = __builtin_amdgcn_mfma_f32_32x32x16_f16(kf6, qf[6], a, 0, 0, 0);
        a = __builtin_amdgcn_mfma_f32_32x32x16_f16(kf7, qf[7], a, 0, 0, 0);
        return a;
    };

    #pragma unroll 1
    for (int ph = 0; ph < 2; ++ph) {
        const int qt  = ph ? 15 - p : p;
        const int qw0 = qt * 128 + wv * 32;
        const int qg  = qw0 + l31;
        const int nkt = 4 * qt + 4;
        const int lastt = 4 * qt + wv;      // last tile this wave computes (wave-uniform)

        {
            const float* Qrow = Qb + (size_t)(qw0 + l31) * D_;
            #pragma unroll
            for (int dc = 0; dc < 8; ++dc) {
                const float4 a = *(const float4*)(Qrow + dc * 16 + h * 8);
                const float4 b = *(const float4*)(Qrow + dc * 16 + h * 8 + 4);
                qf[dc] = cvt8(a, b);        // scale folded into K at prep
            }
        }

        f32x16 acc[4];
        #pragma unroll
        for (int dt = 0; dt < 4; ++dt)
            #pragma unroll
            for (int q = 0; q < 16; ++q) acc[dt][q] = 0.f;
        float m_i = -1e30f, l_i = 0.f;

        // ---- prologue: buffers 0,1 filled; tile 2 loads in flight
        __syncthreads();            // prev phase's waves done with all LDS
        issue(0);  writeLds(0);
        issue(1);  writeLds(1);
        if (nkt > 2) issue(2);
        __syncthreads();            // buf0, buf1 ready
        f32x16 sv = qkt(0);

        int bB = 0, bA = 1, bW = 2;     // streamB buf (kt%3), streamA buf, write buf
        for (int kt = 0; kt < nkt; ++kt) {
            __syncthreads();            // iter kt-1 fully done (writes of bW safe)
            if (kt + 2 < nkt) {
                writeLds(bW);           // tile kt+2 (loads issued at iter kt-1)
                if (kt + 3 < nkt) issue(kt + 3);
            }

            __builtin_amdgcn_s_setprio(1);
            // ---- stream A: QK^T tile kt+1 (buf bA, written at iter kt-1)
            f32x16 svn;
            if (kt + 1 < nkt && kt + 1 <= lastt) svn = qkt(bA);

            // ---- stream B: softmax + pack + PV tile kt (buf bB)
            if (kt <= lastt) {
                const int k0 = kt * KVB;
                if (k0 + 31 > qw0) {
                    #pragma unroll
                    for (int q = 0; q < 16; ++q) {
                        const int kg = k0 + (q & 3) + 8 * (q >> 2) + 4 * h;
                        if (kg > qg) sv[q] = -1e30f;
                    }
                }
                // row max (max3 nest) + shfl cross-half
                const float m1 = fmaxf(fmaxf(sv[0], sv[1]), sv[2]);
                const float m2 = fmaxf(fmaxf(sv[3], sv[4]), sv[5]);
                const float m3 = fmaxf(fmaxf(sv[6], sv[7]), sv[8]);
                const float m4 = fmaxf(fmaxf(sv[9], sv[10]), sv[11]);
                const float m5 = fmaxf(fmaxf(sv[12], sv[13]), sv[14]);
                float mx = fmaxf(fmaxf(m1, m2), m3);
                mx = fmaxf(fmaxf(mx, m4), m5);
                mx = fmaxf(mx, sv[15]);
                mx = fmaxf(mx, __shfl_xor(mx, 32));
                if (!__all(mx - m_i <= 8.0f)) {       // defer-max (T13)
                    const float mn = fmaxf(m_i, mx);
                    const float al = exp2f(m_i - mn);
                    m_i = mn;
                    l_i *= al;
                    float arow[16];
                    #pragma unroll
                    for (int q = 0; q < 16; ++q)
                        arow[q] = __shfl(al, (q & 3) + 8 * (q >> 2) + 4 * h);
                    #pragma unroll
                    for (int dt = 0; dt < 4; ++dt)
                        #pragma unroll
                        for (int q = 0; q < 16; ++q) acc[dt][q] *= arow[q];
                }
                // exp + row sum (tree) + shfl cross-half
                #pragma unroll
                for (int q = 0; q < 16; ++q) sv[q] = exp2f(sv[q] - m_i);
                float s8[8];
                #pragma unroll
                for (int q = 0; q < 8; ++q) s8[q] = sv[2 * q] + sv[2 * q + 1];
                #pragma unroll
                for (int q = 0; q < 4; ++q) s8[q] += s8[q + 4];
                s8[0] += s8[2]; s8[1] += s8[3];
                float rsum = s8[0] + s8[1];
                rsum += __shfl_xor(rsum, 32);
                l_i += rsum;
                // P -> f16 A-frags: zero-shuffle pack (V is pi-permuted to match)
                U4 pa0, pa1;
                #pragma unroll
                for (int m = 0; m < 4; ++m) {
                    pa0.i[m] = (int)pk2(sv[2 * m],     sv[2 * m + 1]);
                    pa1.i[m] = (int)pk2(sv[8 + 2 * m], sv[9 + 2 * m]);
                }
                // PV (tile kt, buf bB): batch all 8 vb fragment loads, then MFMA
                const f16* vbase = &Vt[bB][l31 * VTSTR + h * 8];
                f16x8 vb0 = *(const f16x8*)(vbase + 0 * 32 * VTSTR);
                f16x8 vb1 = *(const f16x8*)(vbase + 0 * 32 * VTSTR + 16);
                f16x8 vb2 = *(const f16x8*)(vbase + 1 * 32 * VTSTR);
                f16x8 vb3 = *(const f16x8*)(vbase + 1 * 32 * VTSTR + 16);
                f16x8 vb4 = *(const f16x8*)(vbase + 2 * 32 * VTSTR);
                f16x8 vb5 = *(const f16x8*)(vbase + 2 * 32 * VTSTR + 16);
                f16x8 vb6 = *(const f16x8*)(vbase + 3 * 32 * VTSTR);
                f16x8 vb7 = *(const f16x8*)(vbase + 3 * 32 * VTSTR + 16);
                acc[0] = __builtin_amdgcn_mfma_f32_32x32x16_f16(pa0.h, vb0, acc[0], 0, 0, 0);
                acc[0] = __builtin_amdgcn_mfma_f32_32x32x16_f16(pa1.h, vb1, acc[0], 0, 0, 0);
                acc[1] = __builtin_amdgcn_mfma_f32_32x32x16_f16(pa0.h, vb2, acc[1], 0, 0, 0);
                acc[1] = __builtin_amdgcn_mfma_f32_32x32x16_f16(pa1.h, vb3, acc[1], 0, 0, 0);
                acc[2] = __builtin_amdgcn_mfma_f32_32x32x16_f16(pa0.h, vb4, acc[2], 0, 0, 0);
                acc[2] = __builtin_amdgcn_mfma_f32_32x32x16_f16(pa1.h, vb5, acc[2], 0, 0, 0);
                acc[3] = __builtin_amdgcn_mfma_f32_32x32x16_f16(pa0.h, vb6, acc[3], 0, 0, 0);
                acc[3] = __builtin_amdgcn_mfma_f32_32x32x16_f16(pa1.h, vb7, acc[3], 0, 0, 0);
            }
            __builtin_amdgcn_s_setprio(0);

            if (kt + 1 < nkt) sv = svn;
            const int t = bB; bB = bA; bA = bW; bW = t;   // rotate %3
        }

        // epilogue (row=(q&3)+8*(q>>2)+4h, col=dt*32+l31)
        float li[16];
        #pragma unroll
        for (int q = 0; q < 16; ++q) {
            const float lv = __shfl(l_i, (q & 3) + 8 * (q >> 2) + 4 * h);
            li[q] = 1.0f / lv;
        }
        #pragma unroll
        for (int dt = 0; dt < 4; ++dt)
            #pragma unroll
            for (int q = 0; q < 16; ++q) {
                const int row = qw0 + (q & 3) + 8 * (q >> 2) + 4 * h;
                Ob[(size_t)row * D_ + dt * 32 + l31] = acc[dt][q] * li[q];
            }
    }
}

// ---------------- fallback (tiny ws): f32 in-loop staging, single pass ----------------
__global__ __launch_bounds__(256, 3)
void fattn5(const float* __restrict__ Qg, const float* __restrict__ Kg,
            const float* __restrict__ Vg, float* __restrict__ Og)
{
    __shared__ __align__(16) f16 Klds[2][KVB * KSTR];
    __shared__ __align__(16) f16 Vt[2][128 * VTSTR];
    const int id  = blockIdx.x;
    const int xcd = id & 7;
    const int w   = id >> 3;
    const int qt  = 15 - (w & 15);
    const int bh  = xcd + 8 * (w >> 4);
    const int tid  = threadIdx.x;
    const int lane = tid & 63;
    const int wv   = tid >> 6;
    const int l31  = lane & 31;
    const int h    = lane >> 5;
    const int qw0 = qt * 128 + wv * 32;
    const int qg  = qw0 + l31;
    const size_t base = (size_t)bh * S_ * D_;
    const float* Qb = Qg + base;
    const float* Kb = Kg + base;
    const float* Vb = Vg + base;
    float*       Ob = Og + base;
    const int nkt = 4 * qt + 4;
    float4 kr[4];
    float  vr[16];
    auto issue = [&](int kt) {
        const int k0n = kt * KVB;
        #pragma unroll
        for (int it = 0; it < 2; ++it) {
            const int idx  = tid + it * 256;
            const int krow = idx >> 4;
            const int c8   = idx & 15;
            const float* kp = Kb + (size_t)(k0n + krow) * D_ + c8 * 8;
            kr[it * 2]     = *(const float4*)kp;
            kr[it * 2 + 1] = *(const float4*)(kp + 4);
            const int d  = idx & 127;
            const int k8 = idx >> 7;
            const float* vp = Vb + (size_t)(k0n + k8 * 8) * D_ + d;
            #pragma unroll
            for (int e = 0; e < 8; ++e) vr[it * 8 + e] = vp[(size_t)e * D_];
        }
    };
    auto writeLds = [&](int buf) {
        #pragma unroll
        for (int it = 0; it < 2; ++it) {
            const int idx  = tid + it * 256;
            const int krow = idx >> 4;
            const int c8   = idx & 15;
            *(f16x8*)&Klds[buf][krow * KSTR + c8 * 8] = cvt8(kr[it * 2], kr[it * 2 + 1]);
            const int d  = idx & 127;
            const int k8 = idx >> 7;
            f16x8 vh;
            #pragma unroll
            for (int e = 0; e < 8; ++e) vh[e] = (f16)vr[it * 8 + e];
            *(f16x8*)&Vt[buf][d * VTSTR + k8 * 8] = vh;
        }
    };
    const float qmul = 0.08838834764831845f * 1.4426950408889634f;
    f16x8 qf[8];
    {
        const float* Qrow = Qb + (size_t)(qw0 + l31) * D_;
        #pragma unroll
        for (int dc = 0; dc < 8; ++dc) {
            const float4 a = *(const float4*)(Qrow + dc * 16 + h * 8);
            const float4 b = *(const float4*)(Qrow + dc * 16 + h * 8 + 4);
            f16x8 q;
            q[0] = (f16)(a.x * qmul); q[1] = (f16)(a.y * qmul);
            q[2] = (f16)(a.z * qmul); q[3] = (f16)(a.w * qmul);
            q[4] = (f16)(b.x * qmul); q[5] = (f16)(b.y * qmul);
            q[6] = (f16)(b.z * qmul); q[7] = (f16)(b.w * qmul);
            qf[dc] = q;
        }
    }
    f32x16 acc[4];
    #pragma unroll
    for (int dt = 0; dt < 4; ++dt)
        #pragma unroll
        for (int q = 0; q < 16; ++q) acc[dt][q] = 0.f;
    float m_i = -1e30f, l_i = 0.f;
    issue(0);
    writeLds(0);
    if (nkt > 1) issue(1);
    __syncthreads();
    for (int kt = 0; kt < nkt; ++kt) {
        const int k0  = kt * KVB;
        const int cur = kt & 1;
        if (k0 <= qw0 + 31) {
            f32x16 sv;
            #pragma unroll
            for (int q = 0; q < 16; ++q) sv[q] = 0.f;
            #pragma unroll
            for (int dc = 0; dc < 8; ++dc) {
                const f16x8 kf = *(const f16x8*)&Klds[cur][l31 * KSTR + dc * 16 + h * 8];
                sv = __builtin_amdgcn_mfma_f32_32x32x16_f16(kf, qf[dc], sv, 0, 0, 0);
            }
            if (k0 + 31 > qw0) {
                #pragma unroll
                for (int q = 0; q < 16; ++q) {
                    const int kg = k0 + (q & 3) + 8 * (q >> 2) + 4 * h;
                    if (kg > qg) sv[q] = -1e30f;
                }
            }
            float mx = sv[0];
            #pragma unroll
            for (int q = 1; q < 16; ++q) mx = fmaxf(mx, sv[q]);
            mx = fmaxf(mx, __shfl_xor(mx, 32));
            if (!__all(mx - m_i <= 8.0f)) {
                const float mn = fmaxf(m_i, mx);
                const float al = exp2f(m_i - mn);
                m_i = mn;
                l_i *= al;
                float arow[16];
                #pragma unroll
                for (int q = 0; q < 16; ++q)
                    arow[q] = __shfl(al, (q & 3) + 8 * (q >> 2) + 4 * h);
                #pragma unroll
                for (int dt = 0; dt < 4; ++dt)
                    #pragma unroll
                    for (int q = 0; q < 16; ++q) acc[dt][q] *= arow[q];
            }
            float rsum = 0.f;
            #pragma unroll
            for (int q = 0; q < 16; ++q) {
                sv[q] = exp2f(sv[q] - m_i);
                rsum += sv[q];
            }
            rsum += __shfl_xor(rsum, 32);
            l_i += rsum;
            U4 pa[2];
            {
                unsigned dwp[8];
                #pragma unroll
                for (int m = 0; m < 8; ++m) dwp[m] = pk2(sv[2 * m], sv[2 * m + 1]);
                #pragma unroll
                for (int hf = 0; hf < 2; ++hf) {
                    const unsigned a0 = dwp[hf * 4 + 0], a1 = dwp[hf * 4 + 1];
                    const unsigned b0 = dwp[hf * 4 + 2], b1 = dwp[hf * 4 + 3];
                    const unsigned sa0 = (unsigned)__shfl_xor((int)a0, 32);
                    const unsigned sa1 = (unsigned)__shfl_xor((int)a1, 32);
                    const unsigned sb0 = (unsigned)__shfl_xor((int)b0, 32);
                    const unsigned sb1 = (unsigned)__shfl_xor((int)b1, 32);
                    i32x4 d;
                    d[0] = h ? (int)sb0 : (int)a0;
                    d[1] = h ? (int)sb1 : (int)a1;
                    d[2] = h ? (int)b0  : (int)sa0;
                    d[3] = h ? (int)b1  : (int)sa1;
                    pa[hf].i = d;
                }
            }
            #pragma unroll
            for (int dt = 0; dt < 4; ++dt) {
                const f16* vrow = &Vt[cur][(dt * 32 + l31) * VTSTR + h * 8];
                const f16x8 vb0 = *(const f16x8*)(vrow + 0);
                const f16x8 vb1 = *(const f16x8*)(vrow + 16);
                acc[dt] = __builtin_amdgcn_mfma_f32_32x32x16_f16(pa[0].h, vb0, acc[dt], 0, 0, 0);
                acc[dt] = __builtin_amdgcn_mfma_f32_32x32x16_f16(pa[1].h, vb1, acc[dt], 0, 0, 0);
            }
        }
        if (kt + 1 < nkt) {
            writeLds(cur ^ 1);
            if (kt + 2 < nkt) issue(kt + 2);
            __syncthreads();
        }
    }
    float li[16];
    #pragma unroll
    for (int q = 0; q < 16; ++q) {
        const float lv = __shfl(l_i, (q & 3) + 8 * (q >> 2) + 4 * h);
        li[q] = 1.0f / lv;
    }
    #pragma unroll
    for (int dt = 0; dt < 4; ++dt)
        #pragma unroll
        for (int q = 0; q < 16; ++q) {
            const int row = qw0 + (q & 3) + 8 * (q >> 2) + 4 * h;
            Ob[(size_t)row * D_ + dt * 32 + l31] = acc[dt][q] * li[q];
        }
}

extern "C" void kernel_launch(void* const* d_in, const int* in_sizes, int n_in,
                              void* d_out, int out_size, void* d_ws, size_t ws_size,
                              hipStream_t stream) {
    (void)in_sizes; (void)n_in; (void)out_size;
    const float* Q = (const float*)d_in[0];
    const float* K = (const float*)d_in[1];
    const float* V = (const float*)d_in[2];
    float* O = (float*)d_out;
    const size_t elems  = (size_t)B_ * H_ * S_ * D_;
    const size_t needKV = elems * 2 * sizeof(f16);     // Kh + Vtt
    if (ws_size >= needKV) {
        f16* Kh  = (f16*)d_ws;
        f16* Vtt = Kh + elems;
        prep<<<dim3(B_ * H_ * (S_ / 64)), dim3(256), 0, stream>>>(K, V, Kh, Vtt);
        fattn20<<<dim3(512), dim3(256), 0, stream>>>(Q, Kh, Vtt, O);
    } else {
        fattn5<<<dim3((S_ / 128) * B_ * H_), dim3(256), 0, stream>>>(Q, K, V, O);
    }
}